// Round 1
// baseline (236.912 us; speedup 1.0000x reference)
//
#include <hip/hip_runtime.h>
#include <hip/hip_bf16.h>

#define N 2048
#define D 64
#define NB 8192                 // histogram bins
#define LOG_N 7.624618986159398f  // ln(2048)

// ws layout (bytes):
//   [0, 32768)          : unsigned hist[NB]
//   [32768, 32832)      : scalars: u[0]=maxsq bits; f[1]=1/hh; f[2]=2/hh
//   [32832, 41024)      : float sqbuf[N]
//   [41024, 565312)     : float wbuf[N*D]   (w_j = t_j + divD_j)
#define SCAL_OFF 32768
#define SQ_OFF   32832
#define WBUF_OFF 41024

__device__ inline float wred64(float v) {
    #pragma unroll
    for (int m = 32; m; m >>= 1) v += __shfl_xor(v, m, 64);
    return v;
}

// ---------------- per-particle prep: sq_j, w_j = D_j s_grad_j + divD_j ----------------
__global__ __launch_bounds__(256) void prep_k(const float* __restrict__ x,
                                              const float* __restrict__ mu,
                                              float* __restrict__ wbuf,
                                              float* __restrict__ sqbuf,
                                              unsigned* __restrict__ scal_u) {
    int w = threadIdx.x >> 6, lane = threadIdx.x & 63;
    int j = blockIdx.x * 4 + w;
    float xv = x[j * D + lane];
    float sg = mu[lane] - xv;                 // s_grad = -(x - mu)
    float sq = wred64(xv * xv);               // ||x_j||^2
    float xd = wred64(xv * sg);               // x . s_grad
    float t  = sg - xv * (xd / sq);           // D_j s_grad_j
    float dv = xv * (-(float)(D - 1) / sq);   // divD_j
    wbuf[j * D + lane] = t + dv;
    if (lane == 0) {
        sqbuf[j] = sq;
        atomicMax(scal_u, __float_as_uint(sq));  // sq > 0 -> uint order == float order
    }
}

// ---------------- histogram of pairwise squared distances ----------------
__global__ __launch_bounds__(256) void hist_k(const float* __restrict__ x,
                                              const float* __restrict__ sqbuf,
                                              const unsigned* __restrict__ scal_u,
                                              unsigned* __restrict__ ghist) {
    __shared__ float xs[64][68];
    __shared__ float xi4[4][68];
    __shared__ float sqs[64];
    __shared__ unsigned lh[NB];
    int tid = threadIdx.x, w = tid >> 6, lane = tid & 63;
    for (int b = tid; b < NB; b += 256) lh[b] = 0u;
    int i = blockIdx.x * 4 + w;
    xi4[w][lane] = x[i * D + lane];
    float sqi = sqbuf[i];
    float maxsq = __uint_as_float(scal_u[0]);
    float top = 4.0f * maxsq + 1e-6f;
    float scale = (float)NB / top;

    for (int jt = 0; jt < N / 64; jt++) {
        __syncthreads();
        #pragma unroll
        for (int q = 0; q < 4; q++) {
            int idx = tid + q * 256;          // 0..1023, 64 rows x 16 float4
            int r = idx >> 4, c4 = idx & 15;
            float4 v = reinterpret_cast<const float4*>(x + (jt * 64 + r) * D)[c4];
            xs[r][c4 * 4 + 0] = v.x; xs[r][c4 * 4 + 1] = v.y;
            xs[r][c4 * 4 + 2] = v.z; xs[r][c4 * 4 + 3] = v.w;
        }
        if (tid < 64) sqs[tid] = sqbuf[jt * 64 + tid];
        __syncthreads();
        float dot = 0.f;
        const float4* xr = reinterpret_cast<const float4*>(xs[lane]);
        const float4* ir = reinterpret_cast<const float4*>(xi4[w]);
        #pragma unroll
        for (int l4 = 0; l4 < 16; l4++) {
            float4 a = ir[l4], b = xr[l4];
            dot += a.x * b.x + a.y * b.y + a.z * b.z + a.w * b.w;
        }
        float pd = fmaxf(sqi + sqs[lane] - 2.f * dot, 0.f);
        int bin = (int)(pd * scale); bin = min(bin, NB - 1);
        atomicAdd(&lh[bin], 1u);
    }
    __syncthreads();
    for (int b = tid; b < NB; b += 256) if (lh[b]) atomicAdd(&ghist[b], lh[b]);
}

// ---------------- median from histogram -> 1/hh, 2/hh ----------------
__global__ __launch_bounds__(256) void scan_k(const unsigned* __restrict__ ghist,
                                              const unsigned* __restrict__ scal_u,
                                              float* __restrict__ scal_f) {
    __shared__ unsigned bins[NB];
    __shared__ unsigned long long csum[256];
    __shared__ unsigned long long pref[257];
    int tid = threadIdx.x;
    unsigned long long s = 0;
    for (int b = 0; b < NB / 256; b++) {
        unsigned v = ghist[tid * (NB / 256) + b];
        bins[tid * (NB / 256) + b] = v;
        s += v;
    }
    csum[tid] = s;
    __syncthreads();
    if (tid == 0) {
        unsigned long long acc = 0;
        for (int c = 0; c < 256; c++) { pref[c] = acc; acc += csum[c]; }
        pref[256] = acc;
        const unsigned long long kq[2] = { (unsigned long long)N * N / 2 - 1,
                                           (unsigned long long)N * N / 2 };
        float maxsq = __uint_as_float(scal_u[0]);
        float top = 4.0f * maxsq + 1e-6f;
        float binw = top / (float)NB;
        float v[2];
        for (int t = 0; t < 2; t++) {
            int c = 0;
            while (c < 255 && pref[c + 1] <= kq[t]) c++;
            unsigned long long acc2 = pref[c];
            int b = c * (NB / 256);
            while (b < NB - 1 && acc2 + bins[b] <= kq[t]) { acc2 += bins[b]; b++; }
            v[t] = ((float)b + 0.5f) * binw;
        }
        float med = 0.5f * (v[0] + v[1]);
        float hh = med / LOG_N + 1e-6f;
        scal_f[1] = 1.0f / hh;
        scal_f[2] = 2.0f / hh;
    }
}

// ---------------- fused SVGD step ----------------
__global__ __launch_bounds__(256) void fused_k(const float* __restrict__ x,
                                               const float* __restrict__ wbuf,
                                               const float* __restrict__ sqbuf,
                                               const float* __restrict__ scal_f,
                                               float* __restrict__ out) {
    __shared__ float xs[64][68];
    __shared__ float wsb[64][68];
    __shared__ float xi4[4][68];
    __shared__ float sqs[64];
    __shared__ float kk[4][64];
    __shared__ float cc[4][64];
    int tid = threadIdx.x, w = tid >> 6, lane = tid & 63;
    int i = blockIdx.x * 4 + w;
    float inv_hh = scal_f[1], thh = scal_f[2];
    xi4[w][lane] = x[i * D + lane];
    float sqi = sqbuf[i];
    float acc1 = 0.f, acc2 = 0.f, rs = 0.f;

    for (int jt = 0; jt < N / 64; jt++) {
        __syncthreads();
        #pragma unroll
        for (int q = 0; q < 4; q++) {
            int idx = tid + q * 256;
            int r = idx >> 4, c4 = idx & 15;
            float4 v = reinterpret_cast<const float4*>(x + (jt * 64 + r) * D)[c4];
            xs[r][c4 * 4 + 0] = v.x; xs[r][c4 * 4 + 1] = v.y;
            xs[r][c4 * 4 + 2] = v.z; xs[r][c4 * 4 + 3] = v.w;
            float4 u = reinterpret_cast<const float4*>(wbuf + (jt * 64 + r) * D)[c4];
            wsb[r][c4 * 4 + 0] = u.x; wsb[r][c4 * 4 + 1] = u.y;
            wsb[r][c4 * 4 + 2] = u.z; wsb[r][c4 * 4 + 3] = u.w;
        }
        if (tid < 64) sqs[tid] = sqbuf[jt * 64 + tid];
        __syncthreads();
        // phase 1: lane = local j; dot_ij over d
        float dot = 0.f;
        const float4* xr = reinterpret_cast<const float4*>(xs[lane]);
        const float4* ir = reinterpret_cast<const float4*>(xi4[w]);
        #pragma unroll
        for (int l4 = 0; l4 < 16; l4++) {
            float4 a = ir[l4], b = xr[l4];
            dot += a.x * b.x + a.y * b.y + a.z * b.z + a.w * b.w;
        }
        float sqj = sqs[lane];
        float pd = fmaxf(sqi + sqj - 2.f * dot, 0.f);
        float k = __expf(-pd * inv_hh);
        rs += k;
        kk[w][lane] = k;
        cc[w][lane] = k * dot / sqj;
        __syncthreads();
        // phase 2: lane = component; accumulate over the 64 j's
        #pragma unroll 4
        for (int j = 0; j < 64; j++) {
            float kj = kk[w][j], cj = cc[w][j];
            acc1 += kj * wsb[j][lane];
            acc2 += cj * xs[j][lane];
        }
    }
    // epilogue
    float rst = wred64(rs);
    float xv = xi4[w][lane];
    float inner = acc1 + (rst * xv - acc2) * thh;
    float xin = wred64(xv * inner);
    float gr = inner - xv * (xin / sqi) - xv * ((float)(D - 1) / sqi);
    float dx = gr * (0.1f / (float)N);
    dx = fminf(fmaxf(dx, -1000.0f), 1000.0f);
    out[i * D + lane] = xv + dx;
}

extern "C" void kernel_launch(void* const* d_in, const int* in_sizes, int n_in,
                              void* d_out, int out_size, void* d_ws, size_t ws_size,
                              hipStream_t stream) {
    const float* x  = (const float*)d_in[0];
    const float* mu = (const float*)d_in[1];
    float* out = (float*)d_out;

    char* ws = (char*)d_ws;
    unsigned* ghist  = (unsigned*)ws;
    unsigned* scal_u = (unsigned*)(ws + SCAL_OFF);
    float*    scal_f = (float*)(ws + SCAL_OFF);
    float*    sqbuf  = (float*)(ws + SQ_OFF);
    float*    wbuf   = (float*)(ws + WBUF_OFF);

    // zero hist + scalar block (ws is poisoned before every call)
    hipMemsetAsync(ws, 0, SCAL_OFF + 64, stream);

    prep_k<<<N / 4, 256, 0, stream>>>(x, mu, wbuf, sqbuf, scal_u);
    hist_k<<<N / 4, 256, 0, stream>>>(x, sqbuf, scal_u, ghist);
    scan_k<<<1, 256, 0, stream>>>(ghist, scal_u, scal_f);
    fused_k<<<N / 4, 256, 0, stream>>>(x, wbuf, sqbuf, scal_f, out);
}

// Round 3
// 155.941 us; speedup vs baseline: 1.5192x; 1.5192x over previous
//
#include <hip/hip_runtime.h>

#define N 2048
#define DIM 64
#define NB 8192
#define LOG_N 7.624618986159398f

typedef short bf16x8 __attribute__((ext_vector_type(8)));
typedef float f32x4 __attribute__((ext_vector_type(4)));
typedef unsigned short u16x8 __attribute__((ext_vector_type(8)));

// ws layout (bytes)
#define HIST_OFF 0            // unsigned hist[8192]            (32768)
#define SCAL_OFF 32768        // u[0]=maxsq bits; f[1]=1/hh; f[2]=2/hh (64)
#define SQ_OFF   32832        // float sq[N]                    (8192)
#define XB_OFF   41024        // bf16 XB[N][64] row-major       (262144)
#define WT_OFF   303168       // bf16 WT[16][64][128] (d-major) (262144)
#define XT_OFF   565312       // bf16 XT[16][64][128]           (262144)
#define P1_OFF   827456       // f32 P1[2][N][64]               (1048576)
#define P2_OFF   1876032      // f32 P2[2][N][64]               (1048576)
#define RS_OFF   2924608      // f32 RS[2][N]                   (16384)

__device__ inline float wred64(float v) {
    #pragma unroll
    for (int m = 32; m; m >>= 1) v += __shfl_xor(v, m, 64);
    return v;
}
__device__ inline unsigned short f2bf(float f) {
    unsigned u = __float_as_uint(f);
    return (unsigned short)((u + 0x7FFFu + ((u >> 16) & 1u)) >> 16);
}

// ---------------- prep: sq, w, bf16 X copies ----------------
__global__ __launch_bounds__(256) void prep_k(const float* __restrict__ x,
                                              const float* __restrict__ mu,
                                              char* __restrict__ ws) {
    unsigned short* XB = (unsigned short*)(ws + XB_OFF);
    unsigned short* WT = (unsigned short*)(ws + WT_OFF);
    unsigned short* XT = (unsigned short*)(ws + XT_OFF);
    float* SQ = (float*)(ws + SQ_OFF);
    unsigned* scal_u = (unsigned*)(ws + SCAL_OFF);
    int w = threadIdx.x >> 6, lane = threadIdx.x & 63;
    int j = blockIdx.x * 4 + w;
    float xv = x[j * DIM + lane];
    float sg = mu[lane] - xv;                       // s_grad
    float sq = wred64(xv * xv);
    float xd = wred64(xv * sg);
    float wv = sg - xv * (xd / sq) - xv * (63.0f / sq);  // D_j s_grad + divD_j
    XB[j * DIM + lane] = f2bf(xv);
    int bo = ((j >> 7) * DIM + lane) * 128 + (j & 127);  // [jt][d][jl]
    XT[bo] = f2bf(xv);
    WT[bo] = f2bf(wv);
    if (lane == 0) { SQ[j] = sq; atomicMax(scal_u, __float_as_uint(sq)); }
}

// ---------------- histogram of pairwise sq dists via MFMA ----------------
__global__ __launch_bounds__(256) void hist_k(char* __restrict__ ws) {
    __shared__ unsigned short s_xi[128 * 64];
    __shared__ unsigned short s_xj[64 * 64];
    __shared__ float s_sqi[128];
    __shared__ float s_sqj[64];
    __shared__ unsigned s_hist[NB];
    const unsigned short* XB = (const unsigned short*)(ws + XB_OFF);
    const float* SQ = (const float*)(ws + SQ_OFF);
    const unsigned* scal_u = (const unsigned*)(ws + SCAL_OFF);
    unsigned* ghist = (unsigned*)(ws + HIST_OFF);
    int tid = threadIdx.x;
    int i0 = (blockIdx.x >> 5) * 128, j0 = (blockIdx.x & 31) * 64;
    for (int b = tid; b < NB; b += 256) s_hist[b] = 0u;
    const u16x8* XBv = (const u16x8*)XB;
    #pragma unroll
    for (int q = 0; q < 4; q++) {
        int idx = tid + q * 256; int r = idx >> 3, c = idx & 7;
        u16x8 v = XBv[(i0 + r) * 8 + c];
        int byt = (c * 16) ^ ((r & 7) << 4);
        *(u16x8*)((char*)s_xi + r * 128 + byt) = v;
    }
    #pragma unroll
    for (int q = 0; q < 2; q++) {
        int idx = tid + q * 256; int r = idx >> 3, c = idx & 7;
        u16x8 v = XBv[(j0 + r) * 8 + c];
        int byt = (c * 16) ^ ((r & 7) << 4);
        *(u16x8*)((char*)s_xj + r * 128 + byt) = v;
    }
    if (tid < 128) s_sqi[tid] = SQ[i0 + tid];
    if (tid >= 128 && tid < 192) s_sqj[tid - 128] = SQ[j0 + tid - 128];
    float maxsq = __uint_as_float(scal_u[0]);
    float scale = (float)NB / (4.0f * maxsq + 1e-6f);
    __syncthreads();
    int lane = tid & 63, w = tid >> 6, lo = lane & 15, hi = lane >> 4;
    f32x4 acc[2][4];
    #pragma unroll
    for (int a = 0; a < 2; a++)
        #pragma unroll
        for (int b = 0; b < 4; b++) acc[a][b] = (f32x4)0.0f;
    #pragma unroll
    for (int kc = 0; kc < 2; kc++) {
        bf16x8 af[2];
        #pragma unroll
        for (int si = 0; si < 2; si++) {
            int row = w * 32 + si * 16 + lo;
            int byt = (kc * 64 + hi * 16) ^ ((row & 7) << 4);
            af[si] = *(const bf16x8*)((const char*)s_xi + row * 128 + byt);
        }
        #pragma unroll
        for (int sj = 0; sj < 4; sj++) {
            int row = sj * 16 + lo;
            int byt = (kc * 64 + hi * 16) ^ ((row & 7) << 4);
            bf16x8 bfr = *(const bf16x8*)((const char*)s_xj + row * 128 + byt);
            #pragma unroll
            for (int si = 0; si < 2; si++)
                acc[si][sj] = __builtin_amdgcn_mfma_f32_16x16x32_bf16(af[si], bfr, acc[si][sj], 0, 0, 0);
        }
    }
    #pragma unroll
    for (int si = 0; si < 2; si++)
        #pragma unroll
        for (int sj = 0; sj < 4; sj++)
            #pragma unroll
            for (int r = 0; r < 4; r++) {
                int il = w * 32 + si * 16 + hi * 4 + r;
                int jl = sj * 16 + lo;
                float pd = fmaxf(s_sqi[il] + s_sqj[jl] - 2.0f * acc[si][sj][r], 0.0f);
                int bin = min((int)(pd * scale), NB - 1);
                atomicAdd(&s_hist[bin], 1u);
            }
    __syncthreads();
    for (int b = tid; b < NB; b += 256) { unsigned v = s_hist[b]; if (v) atomicAdd(&ghist[b], v); }
}

// ---------------- median from histogram -> 1/hh, 2/hh ----------------
__global__ __launch_bounds__(256) void scan_k(char* __restrict__ ws) {
    __shared__ unsigned bins[NB];
    __shared__ unsigned long long csum[256];
    __shared__ unsigned long long pref[257];
    const unsigned* ghist = (const unsigned*)(ws + HIST_OFF);
    const unsigned* scal_u = (const unsigned*)(ws + SCAL_OFF);
    float* scal_f = (float*)(ws + SCAL_OFF);
    int tid = threadIdx.x;
    unsigned long long s = 0;
    for (int b = 0; b < NB / 256; b++) {
        unsigned v = ghist[tid * (NB / 256) + b];
        bins[tid * (NB / 256) + b] = v;
        s += v;
    }
    csum[tid] = s;
    __syncthreads();
    if (tid == 0) {
        unsigned long long acc = 0;
        for (int c = 0; c < 256; c++) { pref[c] = acc; acc += csum[c]; }
        pref[256] = acc;
        const unsigned long long kq[2] = { (unsigned long long)N * N / 2 - 1,
                                           (unsigned long long)N * N / 2 };
        float maxsq = __uint_as_float(scal_u[0]);
        float binw = (4.0f * maxsq + 1e-6f) / (float)NB;
        float v[2];
        for (int t = 0; t < 2; t++) {
            int c = 0;
            while (c < 255 && pref[c + 1] <= kq[t]) c++;
            unsigned long long acc2 = pref[c];
            int b = c * (NB / 256);
            while (b < NB - 1 && acc2 + bins[b] <= kq[t]) { acc2 += bins[b]; b++; }
            v[t] = ((float)b + 0.5f) * binw;
        }
        float med = 0.5f * (v[0] + v[1]);
        float hh = med / LOG_N + 1e-6f;
        scal_f[1] = 1.0f / hh;
        scal_f[2] = 2.0f / hh;
    }
}

// ---------------- main SVGD pass: S, K, C, acc GEMMs via MFMA ----------------
__global__ __launch_bounds__(256) void svgd_k(char* __restrict__ ws) {
    __shared__ unsigned short s_xi[16 * 64];
    __shared__ unsigned short s_xj[128 * 64];
    __shared__ unsigned short s_wt[64 * 128];
    __shared__ unsigned short s_xt[64 * 128];
    __shared__ unsigned short s_k[16 * 128];
    __shared__ unsigned short s_c[16 * 128];
    __shared__ float s_sqj[128];
    __shared__ float s_sqi[16];
    __shared__ float s_red1[16 * 64];
    __shared__ float s_red2[16 * 64];
    __shared__ float s_rs[16];
    const unsigned short* XB = (const unsigned short*)(ws + XB_OFF);
    const unsigned short* WT = (const unsigned short*)(ws + WT_OFF);
    const unsigned short* XT = (const unsigned short*)(ws + XT_OFF);
    const float* SQ = (const float*)(ws + SQ_OFF);
    const float* scal_f = (const float*)(ws + SCAL_OFF);
    float* P1 = (float*)(ws + P1_OFF);
    float* P2 = (float*)(ws + P2_OFF);
    float* RS = (float*)(ws + RS_OFF);
    int tid = threadIdx.x;
    int ib = blockIdx.x >> 1, jh = blockIdx.x & 1;
    int i0 = ib * 8;
    float inv_hh = scal_f[1], thh = scal_f[2];
    for (int q = tid; q < 16 * 64; q += 256) { s_red1[q] = 0.f; s_red2[q] = 0.f; }
    if (tid < 16) s_rs[tid] = 0.f;
    const u16x8* XBv = (const u16x8*)XB;
    if (tid < 64) {                       // 8 real rows of X_I
        int r = tid >> 3, c = tid & 7;
        u16x8 v = XBv[(i0 + r) * 8 + c];
        int byt = (c * 16) ^ ((r & 7) << 4);
        *(u16x8*)((char*)s_xi + r * 128 + byt) = v;
    } else if (tid < 128) {               // zero-pad rows 8..15
        int t = tid - 64; int r = 8 + (t >> 3), c = t & 7;
        int byt = (c * 16) ^ ((r & 7) << 4);
        *(u16x8*)((char*)s_xi + r * 128 + byt) = (u16x8)0;
    }
    if (tid >= 128 && tid < 136) s_sqi[tid - 128] = SQ[i0 + tid - 128];
    if (tid >= 136 && tid < 144) s_sqi[tid - 128] = 1.0f;
    int lane = tid & 63, w = tid >> 6, lo = lane & 15, hi = lane >> 4;
    f32x4 a1[4], a2[4], rsv;
    #pragma unroll
    for (int sd = 0; sd < 4; sd++) { a1[sd] = (f32x4)0.f; a2[sd] = (f32x4)0.f; }
    rsv = (f32x4)0.f;
    bf16x8 ones;
    #pragma unroll
    for (int e = 0; e < 8; e++) ones[e] = (short)0x3F80;

    for (int itr = 0; itr < 8; itr++) {
        int jb = jh * 1024 + itr * 128;
        __syncthreads();                                    // prev iter reads done
        #pragma unroll
        for (int q = 0; q < 4; q++) {                       // X_J rows
            int idx = tid + q * 256; int r = idx >> 3, c = idx & 7;
            u16x8 v = XBv[(jb + r) * 8 + c];
            int byt = (c * 16) ^ ((r & 7) << 4);
            *(u16x8*)((char*)s_xj + r * 128 + byt) = v;
        }
        int jt_g = jb >> 7;
        const u16x8* WTv = (const u16x8*)(WT + jt_g * 64 * 128);
        const u16x8* XTv = (const u16x8*)(XT + jt_g * 64 * 128);
        #pragma unroll
        for (int q = 0; q < 4; q++) {                       // W^T, X^T slices
            int idx = tid + q * 256; int r = idx >> 4, c = idx & 15;
            int byt = (c * 16) ^ ((r & 7) << 4);
            u16x8 v = WTv[r * 16 + c];
            *(u16x8*)((char*)s_wt + r * 256 + byt) = v;
            u16x8 v2 = XTv[r * 16 + c];
            *(u16x8*)((char*)s_xt + r * 256 + byt) = v2;
        }
        if (tid < 128) s_sqj[tid] = SQ[jb + tid];
        __syncthreads();
        // S = X_I . X_J^T for this wave's 32-j slice
        f32x4 sreg[2]; sreg[0] = (f32x4)0.f; sreg[1] = (f32x4)0.f;
        #pragma unroll
        for (int kc = 0; kc < 2; kc++) {
            int bytA = (kc * 64 + hi * 16) ^ ((lo & 7) << 4);
            bf16x8 af = *(const bf16x8*)((const char*)s_xi + lo * 128 + bytA);
            #pragma unroll
            for (int sj = 0; sj < 2; sj++) {
                int rowB = w * 32 + sj * 16 + lo;
                int bytB = (kc * 64 + hi * 16) ^ ((rowB & 7) << 4);
                bf16x8 bfr = *(const bf16x8*)((const char*)s_xj + rowB * 128 + bytB);
                sreg[sj] = __builtin_amdgcn_mfma_f32_16x16x32_bf16(af, bfr, sreg[sj], 0, 0, 0);
            }
        }
        // K = exp(-pd/hh), C = K*dot/sq_j  -> bf16 -> LDS (swizzled)
        #pragma unroll
        for (int sj = 0; sj < 2; sj++) {
            int jl = w * 32 + sj * 16 + lo;
            float sqj = s_sqj[jl];
            #pragma unroll
            for (int r = 0; r < 4; r++) {
                int il = hi * 4 + r;
                float dot = sreg[sj][r];
                float pd = fmaxf(s_sqi[il] + sqj - 2.0f * dot, 0.0f);
                float kv = __expf(-pd * inv_hh);
                float cv = kv * dot / sqj;
                int byt = (jl * 2) ^ ((il & 7) << 4);
                *(unsigned short*)((char*)s_k + il * 256 + byt) = f2bf(kv);
                *(unsigned short*)((char*)s_c + il * 256 + byt) = f2bf(cv);
            }
        }
        __syncthreads();                                    // K/C visible (insurance)
        // acc1 += K.W, acc2 += C.X, rs += K.1 over this wave's 32-j k-slice
        int bytK = w * 64 + hi * 16;
        bf16x8 aK = *(const bf16x8*)((const char*)s_k + lo * 256 + (bytK ^ ((lo & 7) << 4)));
        bf16x8 aC = *(const bf16x8*)((const char*)s_c + lo * 256 + (bytK ^ ((lo & 7) << 4)));
        #pragma unroll
        for (int sd = 0; sd < 4; sd++) {
            int rowB = sd * 16 + lo;
            int bytB = bytK ^ ((rowB & 7) << 4);
            bf16x8 bW = *(const bf16x8*)((const char*)s_wt + rowB * 256 + bytB);
            a1[sd] = __builtin_amdgcn_mfma_f32_16x16x32_bf16(aK, bW, a1[sd], 0, 0, 0);
            bf16x8 bX = *(const bf16x8*)((const char*)s_xt + rowB * 256 + bytB);
            a2[sd] = __builtin_amdgcn_mfma_f32_16x16x32_bf16(aC, bX, a2[sd], 0, 0, 0);
        }
        rsv = __builtin_amdgcn_mfma_f32_16x16x32_bf16(aK, ones, rsv, 0, 0, 0);
    }
    __syncthreads();
    #pragma unroll
    for (int sd = 0; sd < 4; sd++)
        #pragma unroll
        for (int r = 0; r < 4; r++) {
            int il = hi * 4 + r, dd = sd * 16 + lo;
            atomicAdd(&s_red1[il * 64 + dd], a1[sd][r]);
            atomicAdd(&s_red2[il * 64 + dd], a2[sd][r]);
        }
    if (lo == 0) {
        #pragma unroll
        for (int r = 0; r < 4; r++) atomicAdd(&s_rs[hi * 4 + r], rsv[r]);
    }
    __syncthreads();
    for (int q = tid; q < 8 * 64; q += 256) {
        int row = q >> 6, dd = q & 63;
        P1[(jh * N + i0 + row) * 64 + dd] = s_red1[row * 64 + dd];
        P2[(jh * N + i0 + row) * 64 + dd] = s_red2[row * 64 + dd];
    }
    if (tid < 8) RS[jh * N + i0 + tid] = s_rs[tid];
}

// ---------------- epilogue: combine halves, projector, step ----------------
__global__ __launch_bounds__(256) void epi_k(const float* __restrict__ x,
                                             const char* __restrict__ ws,
                                             float* __restrict__ out) {
    const float* P1 = (const float*)(ws + P1_OFF);
    const float* P2 = (const float*)(ws + P2_OFF);
    const float* RS = (const float*)(ws + RS_OFF);
    const float* SQ = (const float*)(ws + SQ_OFF);
    const float* scal_f = (const float*)(ws + SCAL_OFF);
    int w = threadIdx.x >> 6, lane = threadIdx.x & 63;
    int row = blockIdx.x * 4 + w;
    float thh = scal_f[2];
    float sqi = SQ[row];
    float xv = x[row * DIM + lane];
    float acc1 = P1[row * 64 + lane] + P1[(N + row) * 64 + lane];
    float acc2 = P2[row * 64 + lane] + P2[(N + row) * 64 + lane];
    float rs = RS[row] + RS[N + row];
    float inner = acc1 + (rs * xv - acc2) * thh;
    float xin = wred64(xv * inner);
    float gr = inner - xv * ((xin + 63.0f) / sqi);
    float dx = gr * (0.1f / (float)N);
    dx = fminf(fmaxf(dx, -1000.0f), 1000.0f);
    out[row * DIM + lane] = xv + dx;
}

extern "C" void kernel_launch(void* const* d_in, const int* in_sizes, int n_in,
                              void* d_out, int out_size, void* d_ws, size_t ws_size,
                              hipStream_t stream) {
    const float* x  = (const float*)d_in[0];
    const float* mu = (const float*)d_in[1];
    float* out = (float*)d_out;
    char* ws = (char*)d_ws;

    hipMemsetAsync(ws, 0, SCAL_OFF + 64, stream);   // hist + scalars

    prep_k<<<N / 4, 256, 0, stream>>>(x, mu, ws);
    hist_k<<<(N / 128) * (N / 64), 256, 0, stream>>>(ws);
    scan_k<<<1, 256, 0, stream>>>(ws);
    svgd_k<<<(N / 8) * 2, 256, 0, stream>>>(ws);
    epi_k<<<N / 4, 256, 0, stream>>>(x, ws, out);
}

// Round 4
// 126.941 us; speedup vs baseline: 1.8663x; 1.2285x over previous
//
#include <hip/hip_runtime.h>

#define N 2048
#define DIM 64
#define NB 8192
#define LOG_N 7.624618986159398f

typedef short bf16x8 __attribute__((ext_vector_type(8)));
typedef float f32x4 __attribute__((ext_vector_type(4)));
typedef unsigned short u16x8 __attribute__((ext_vector_type(8)));

// ws layout (bytes)
#define HIST_OFF 0            // unsigned hist[8192]            (32768)
#define SCAL_OFF 32768        // u[0]=maxsq bits; f[1]=1/hh; f[2]=2/hh (64)
#define SQ_OFF   32832        // float sq[N]                    (8192)
#define XB_OFF   41024        // bf16 XB[N][64] row-major       (262144)
#define WT_OFF   303168       // bf16 WT[16][64][128] (d-major) (262144)
#define XT_OFF   565312       // bf16 XT[16][64][128]           (262144)
#define P1_OFF   827456       // f32 P1[2][N][64]               (1048576)
#define P2_OFF   1876032      // f32 P2[2][N][64]               (1048576)
#define RS_OFF   2924608      // f32 RS[2][N]                   (16384)

__device__ inline float wred64(float v) {
    #pragma unroll
    for (int m = 32; m; m >>= 1) v += __shfl_xor(v, m, 64);
    return v;
}
__device__ inline unsigned short f2bf(float f) {
    unsigned u = __float_as_uint(f);
    return (unsigned short)((u + 0x7FFFu + ((u >> 16) & 1u)) >> 16);
}

// barrier that does NOT drain vmcnt (keeps prefetch loads in flight)
#define BAR() do { \
    __builtin_amdgcn_sched_barrier(0); \
    asm volatile("s_waitcnt lgkmcnt(0)" ::: "memory"); \
    __builtin_amdgcn_s_barrier(); \
    __builtin_amdgcn_sched_barrier(0); \
} while (0)

// ---------------- prep: sq, w, bf16 X copies ----------------
__global__ __launch_bounds__(256) void prep_k(const float* __restrict__ x,
                                              const float* __restrict__ mu,
                                              char* __restrict__ ws) {
    unsigned short* XB = (unsigned short*)(ws + XB_OFF);
    unsigned short* WT = (unsigned short*)(ws + WT_OFF);
    unsigned short* XT = (unsigned short*)(ws + XT_OFF);
    float* SQ = (float*)(ws + SQ_OFF);
    unsigned* scal_u = (unsigned*)(ws + SCAL_OFF);
    int w = threadIdx.x >> 6, lane = threadIdx.x & 63;
    int j = blockIdx.x * 4 + w;
    float xv = x[j * DIM + lane];
    float sg = mu[lane] - xv;                       // s_grad
    float sq = wred64(xv * xv);
    float xd = wred64(xv * sg);
    float wv = sg - xv * (xd / sq) - xv * (63.0f / sq);  // D_j s_grad + divD_j
    XB[j * DIM + lane] = f2bf(xv);
    int bo = ((j >> 7) * DIM + lane) * 128 + (j & 127);  // [jt][d][jl]
    XT[bo] = f2bf(xv);
    WT[bo] = f2bf(wv);
    if (lane == 0) { SQ[j] = sq; atomicMax(scal_u, __float_as_uint(sq)); }
}

// ---------------- histogram of pairwise sq dists (i subsampled by 4) ----------------
__global__ __launch_bounds__(256) void hist_k(char* __restrict__ ws) {
    __shared__ unsigned short s_xi[128 * 64];
    __shared__ unsigned short s_xj[64 * 64];
    __shared__ float s_sqi[128];
    __shared__ float s_sqj[64];
    __shared__ unsigned s_hist[NB];
    const unsigned short* XB = (const unsigned short*)(ws + XB_OFF);
    const float* SQ = (const float*)(ws + SQ_OFF);
    const unsigned* scal_u = (const unsigned*)(ws + SCAL_OFF);
    unsigned* ghist = (unsigned*)(ws + HIST_OFF);
    int tid = threadIdx.x;
    int i0 = (blockIdx.x >> 5) * 128;             // sampled-row base (sampled rows = 4*r)
    int j0 = (blockIdx.x & 31) * 64;
    for (int b = tid; b < NB; b += 256) s_hist[b] = 0u;
    const u16x8* XBv = (const u16x8*)XB;
    #pragma unroll
    for (int q = 0; q < 4; q++) {
        int idx = tid + q * 256; int r = idx >> 3, c = idx & 7;
        u16x8 v = XBv[(4 * (i0 + r)) * 8 + c];
        int byt = (c * 16) ^ ((r & 7) << 4);
        *(u16x8*)((char*)s_xi + r * 128 + byt) = v;
    }
    #pragma unroll
    for (int q = 0; q < 2; q++) {
        int idx = tid + q * 256; int r = idx >> 3, c = idx & 7;
        u16x8 v = XBv[(j0 + r) * 8 + c];
        int byt = (c * 16) ^ ((r & 7) << 4);
        *(u16x8*)((char*)s_xj + r * 128 + byt) = v;
    }
    if (tid < 128) s_sqi[tid] = SQ[4 * (i0 + tid)];
    if (tid >= 128 && tid < 192) s_sqj[tid - 128] = SQ[j0 + tid - 128];
    float maxsq = __uint_as_float(scal_u[0]);
    float scale = (float)NB / (4.0f * maxsq + 1e-6f);
    __syncthreads();
    int lane = tid & 63, w = tid >> 6, lo = lane & 15, hi = lane >> 4;
    f32x4 acc[2][4];
    #pragma unroll
    for (int a = 0; a < 2; a++)
        #pragma unroll
        for (int b = 0; b < 4; b++) acc[a][b] = (f32x4)0.0f;
    #pragma unroll
    for (int kc = 0; kc < 2; kc++) {
        bf16x8 af[2];
        #pragma unroll
        for (int si = 0; si < 2; si++) {
            int row = w * 32 + si * 16 + lo;
            int byt = (kc * 64 + hi * 16) ^ ((row & 7) << 4);
            af[si] = *(const bf16x8*)((const char*)s_xi + row * 128 + byt);
        }
        #pragma unroll
        for (int sj = 0; sj < 4; sj++) {
            int row = sj * 16 + lo;
            int byt = (kc * 64 + hi * 16) ^ ((row & 7) << 4);
            bf16x8 bfr = *(const bf16x8*)((const char*)s_xj + row * 128 + byt);
            #pragma unroll
            for (int si = 0; si < 2; si++)
                acc[si][sj] = __builtin_amdgcn_mfma_f32_16x16x32_bf16(af[si], bfr, acc[si][sj], 0, 0, 0);
        }
    }
    #pragma unroll
    for (int si = 0; si < 2; si++)
        #pragma unroll
        for (int sj = 0; sj < 4; sj++)
            #pragma unroll
            for (int r = 0; r < 4; r++) {
                int il = w * 32 + si * 16 + hi * 4 + r;
                int jl = sj * 16 + lo;
                float pd = fmaxf(s_sqi[il] + s_sqj[jl] - 2.0f * acc[si][sj][r], 0.0f);
                int bin = min((int)(pd * scale), NB - 1);
                atomicAdd(&s_hist[bin], 1u);
            }
    __syncthreads();
    for (int b = tid; b < NB; b += 256) { unsigned v = s_hist[b]; if (v) atomicAdd(&ghist[b], v); }
}

// ---------------- median from histogram -> 1/hh, 2/hh ----------------
__global__ __launch_bounds__(256) void scan_k(char* __restrict__ ws) {
    __shared__ unsigned bins[NB];
    __shared__ unsigned long long csum[256];
    __shared__ unsigned long long pref[257];
    const unsigned* ghist = (const unsigned*)(ws + HIST_OFF);
    const unsigned* scal_u = (const unsigned*)(ws + SCAL_OFF);
    float* scal_f = (float*)(ws + SCAL_OFF);
    int tid = threadIdx.x;
    unsigned long long s = 0;
    for (int b = 0; b < NB / 256; b++) {
        unsigned v = ghist[tid * (NB / 256) + b];
        bins[tid * (NB / 256) + b] = v;
        s += v;
    }
    csum[tid] = s;
    __syncthreads();
    if (tid == 0) {
        unsigned long long acc = 0;
        for (int c = 0; c < 256; c++) { pref[c] = acc; acc += csum[c]; }
        pref[256] = acc;
        unsigned long long cnt = pref[256];
        const unsigned long long kq[2] = { cnt / 2 - 1, cnt / 2 };
        float maxsq = __uint_as_float(scal_u[0]);
        float binw = (4.0f * maxsq + 1e-6f) / (float)NB;
        float v[2];
        for (int t = 0; t < 2; t++) {
            int c = 0;
            while (c < 255 && pref[c + 1] <= kq[t]) c++;
            unsigned long long acc2 = pref[c];
            int b = c * (NB / 256);
            while (b < NB - 1 && acc2 + bins[b] <= kq[t]) { acc2 += bins[b]; b++; }
            v[t] = ((float)b + 0.5f) * binw;
        }
        float med = 0.5f * (v[0] + v[1]);
        float hh = med / LOG_N + 1e-6f;
        scal_f[1] = 1.0f / hh;
        scal_f[2] = 2.0f / hh;
    }
}

// ---------------- main SVGD pass: M=16 real rows, reg-staged double-buffer ----------------
__global__ __launch_bounds__(256) void svgd_k(char* __restrict__ ws) {
    __shared__ unsigned short s_xi[16 * 64];     // 2 KB
    __shared__ unsigned short s_xj[128 * 64];    // 16 KB
    __shared__ unsigned short s_wt[64 * 128];    // 16 KB
    __shared__ unsigned short s_xt[64 * 128];    // 16 KB
    __shared__ unsigned short s_k[16 * 128];     // 4 KB
    __shared__ unsigned short s_c[16 * 128];     // 4 KB
    __shared__ float s_red[2][16 * 64];          // 8 KB
    __shared__ float s_rs[16];
    const unsigned short* XB = (const unsigned short*)(ws + XB_OFF);
    const unsigned short* WTp = (const unsigned short*)(ws + WT_OFF);
    const unsigned short* XTp = (const unsigned short*)(ws + XT_OFF);
    const float* SQ = (const float*)(ws + SQ_OFF);
    const float* scal_f = (const float*)(ws + SCAL_OFF);
    float* P1 = (float*)(ws + P1_OFF);
    float* P2 = (float*)(ws + P2_OFF);
    float* RS = (float*)(ws + RS_OFF);
    int tid = threadIdx.x;
    int ib = blockIdx.x >> 1, jh = blockIdx.x & 1;
    int i0 = ib * 16;
    int jb0 = jh * 1024;
    int lane = tid & 63, w = tid >> 6, lo = lane & 15, hi = lane >> 4;
    const u16x8* XBv = (const u16x8*)XB;

    u16x8 sA[12], sB[12];
    float sqA[2], sqB[2];

#define LOADT(S, SQR, jb) do { \
    int _jt = (jb) >> 7; \
    const u16x8* _WTv = (const u16x8*)WTp + _jt * 1024; \
    const u16x8* _XTv = (const u16x8*)XTp + _jt * 1024; \
    _Pragma("unroll") \
    for (int q = 0; q < 4; q++) { int idx = tid + q * 256; int r = idx >> 3, c = idx & 7; \
        S[q] = XBv[((jb) + r) * 8 + c]; } \
    _Pragma("unroll") \
    for (int q = 0; q < 4; q++) { int idx = tid + q * 256; int r = idx >> 4, c = idx & 15; \
        S[4 + q] = _WTv[r * 16 + c]; S[8 + q] = _XTv[r * 16 + c]; } \
    SQR[0] = SQ[(jb) + w * 32 + lo]; \
    SQR[1] = SQ[(jb) + w * 32 + 16 + lo]; \
} while (0)

#define STORET(S) do { \
    _Pragma("unroll") \
    for (int q = 0; q < 4; q++) { int idx = tid + q * 256; int r = idx >> 3, c = idx & 7; \
        *(u16x8*)((char*)s_xj + r * 128 + ((c * 16) ^ ((r & 7) << 4))) = S[q]; } \
    _Pragma("unroll") \
    for (int q = 0; q < 4; q++) { int idx = tid + q * 256; int r = idx >> 4, c = idx & 15; \
        int byt = (c * 16) ^ ((r & 7) << 4); \
        *(u16x8*)((char*)s_wt + r * 256 + byt) = S[4 + q]; \
        *(u16x8*)((char*)s_xt + r * 256 + byt) = S[8 + q]; } \
} while (0)

    // prologue: issue first tile's loads ASAP, then fixed per-block setup
    LOADT(sA, sqA, jb0);
    if (tid < 128) {                    // stage X_I (16 real rows)
        int r = tid >> 3, c = tid & 7;
        u16x8 v = XBv[(i0 + r) * 8 + c];
        int byt = (c * 16) ^ ((r & 7) << 4);
        *(u16x8*)((char*)s_xi + r * 128 + byt) = v;
    }
    for (int q = tid; q < 16 * 64; q += 256) { s_red[0][q] = 0.f; s_red[1][q] = 0.f; }
    if (tid < 16) s_rs[tid] = 0.f;
    float inv_hh = scal_f[1];
    float sqi_r[4];
    #pragma unroll
    for (int r = 0; r < 4; r++) sqi_r[r] = SQ[i0 + hi * 4 + r];
    BAR();
    bf16x8 af[2];
    #pragma unroll
    for (int kc = 0; kc < 2; kc++)
        af[kc] = *(const bf16x8*)((const char*)s_xi + lo * 128 + ((kc * 64 + hi * 16) ^ ((lo & 7) << 4)));

    f32x4 a1[4], a2[4], rsv;
    #pragma unroll
    for (int sd = 0; sd < 4; sd++) { a1[sd] = (f32x4)0.f; a2[sd] = (f32x4)0.f; }
    rsv = (f32x4)0.f;
    bf16x8 ones;
    #pragma unroll
    for (int e = 0; e < 8; e++) ones[e] = (short)0x3F80;

#define COMPUTE(jb, SQR) do { \
    f32x4 sreg[2]; sreg[0] = (f32x4)0.f; sreg[1] = (f32x4)0.f; \
    _Pragma("unroll") \
    for (int kc = 0; kc < 2; kc++) { \
        _Pragma("unroll") \
        for (int sj = 0; sj < 2; sj++) { \
            int rowB = w * 32 + sj * 16 + lo; \
            bf16x8 bfr = *(const bf16x8*)((const char*)s_xj + rowB * 128 + ((kc * 64 + hi * 16) ^ ((rowB & 7) << 4))); \
            sreg[sj] = __builtin_amdgcn_mfma_f32_16x16x32_bf16(af[kc], bfr, sreg[sj], 0, 0, 0); \
        } \
    } \
    _Pragma("unroll") \
    for (int sj = 0; sj < 2; sj++) { \
        int jl = w * 32 + sj * 16 + lo; \
        float sqj = SQR[sj]; \
        float rq = 1.0f / sqj; \
        _Pragma("unroll") \
        for (int r = 0; r < 4; r++) { \
            int il = hi * 4 + r; \
            float dot = sreg[sj][r]; \
            float pd = fmaxf(sqi_r[r] + sqj - 2.0f * dot, 0.0f); \
            float kv = __expf(-pd * inv_hh); \
            float cv = kv * dot * rq; \
            int byt = (jl * 2) ^ ((il & 7) << 4); \
            *(unsigned short*)((char*)s_k + il * 256 + byt) = f2bf(kv); \
            *(unsigned short*)((char*)s_c + il * 256 + byt) = f2bf(cv); \
        } \
    } \
    int bytK = (w * 64 + hi * 16) ^ ((lo & 7) << 4); \
    bf16x8 aK = *(const bf16x8*)((const char*)s_k + lo * 256 + bytK); \
    bf16x8 aC = *(const bf16x8*)((const char*)s_c + lo * 256 + bytK); \
    _Pragma("unroll") \
    for (int sd = 0; sd < 4; sd++) { \
        int rowB = sd * 16 + lo; \
        int byt = (w * 64 + hi * 16) ^ ((rowB & 7) << 4); \
        bf16x8 bW = *(const bf16x8*)((const char*)s_wt + rowB * 256 + byt); \
        a1[sd] = __builtin_amdgcn_mfma_f32_16x16x32_bf16(aK, bW, a1[sd], 0, 0, 0); \
        bf16x8 bX = *(const bf16x8*)((const char*)s_xt + rowB * 256 + byt); \
        a2[sd] = __builtin_amdgcn_mfma_f32_16x16x32_bf16(aC, bX, a2[sd], 0, 0, 0); \
    } \
    rsv = __builtin_amdgcn_mfma_f32_16x16x32_bf16(aK, ones, rsv, 0, 0, 0); \
} while (0)

    // main loop: 8 j-tiles of 128, double-buffered (A/B), loads prefetched 1 tile ahead
    for (int m = 0; m < 4; m++) {
        int tA = 2 * m;
        LOADT(sB, sqB, jb0 + (tA + 1) * 128);        // prefetch t+1 (always valid, tA<=6)
        STORET(sA);                                   // compiler waits sA's vmcnt
        BAR();
        COMPUTE(jb0 + tA * 128, sqA);
        BAR();
        if (tA + 2 < 8) LOADT(sA, sqA, jb0 + (tA + 2) * 128);
        STORET(sB);
        BAR();
        COMPUTE(jb0 + (tA + 1) * 128, sqB);
        BAR();
    }

    // cross-wave reduction (j-slices) in LDS
    #pragma unroll
    for (int sd = 0; sd < 4; sd++)
        #pragma unroll
        for (int r = 0; r < 4; r++) {
            int il = hi * 4 + r, dd = sd * 16 + lo;
            atomicAdd(&s_red[0][il * 64 + dd], a1[sd][r]);
            atomicAdd(&s_red[1][il * 64 + dd], a2[sd][r]);
        }
    if (lo == 0) {
        #pragma unroll
        for (int r = 0; r < 4; r++) atomicAdd(&s_rs[hi * 4 + r], rsv[r]);
    }
    BAR();
    for (int q = tid; q < 16 * 64; q += 256) {
        int row = q >> 6, dd = q & 63;
        P1[(jh * N + i0 + row) * 64 + dd] = s_red[0][q];
        P2[(jh * N + i0 + row) * 64 + dd] = s_red[1][q];
    }
    if (tid < 16) RS[jh * N + i0 + tid] = s_rs[tid];
#undef LOADT
#undef STORET
#undef COMPUTE
}

// ---------------- epilogue: combine halves, projector, step ----------------
__global__ __launch_bounds__(256) void epi_k(const float* __restrict__ x,
                                             const char* __restrict__ ws,
                                             float* __restrict__ out) {
    const float* P1 = (const float*)(ws + P1_OFF);
    const float* P2 = (const float*)(ws + P2_OFF);
    const float* RS = (const float*)(ws + RS_OFF);
    const float* SQ = (const float*)(ws + SQ_OFF);
    const float* scal_f = (const float*)(ws + SCAL_OFF);
    int w = threadIdx.x >> 6, lane = threadIdx.x & 63;
    int row = blockIdx.x * 4 + w;
    float thh = scal_f[2];
    float sqi = SQ[row];
    float xv = x[row * DIM + lane];
    float acc1 = P1[row * 64 + lane] + P1[(N + row) * 64 + lane];
    float acc2 = P2[row * 64 + lane] + P2[(N + row) * 64 + lane];
    float rs = RS[row] + RS[N + row];
    float inner = acc1 + (rs * xv - acc2) * thh;
    float xin = wred64(xv * inner);
    float gr = inner - xv * ((xin + 63.0f) / sqi);
    float dx = gr * (0.1f / (float)N);
    dx = fminf(fmaxf(dx, -1000.0f), 1000.0f);
    out[row * DIM + lane] = xv + dx;
}

extern "C" void kernel_launch(void* const* d_in, const int* in_sizes, int n_in,
                              void* d_out, int out_size, void* d_ws, size_t ws_size,
                              hipStream_t stream) {
    const float* x  = (const float*)d_in[0];
    const float* mu = (const float*)d_in[1];
    float* out = (float*)d_out;
    char* ws = (char*)d_ws;

    hipMemsetAsync(ws, 0, SCAL_OFF + 64, stream);   // hist + scalars

    prep_k<<<N / 4, 256, 0, stream>>>(x, mu, ws);
    hist_k<<<(512 / 128) * (N / 64), 256, 0, stream>>>(ws);
    scan_k<<<1, 256, 0, stream>>>(ws);
    svgd_k<<<(N / 16) * 2, 256, 0, stream>>>(ws);
    epi_k<<<N / 4, 256, 0, stream>>>(x, ws, out);
}